// Round 1
// baseline (204.179 us; speedup 1.0000x reference)
//
#include <hip/hip_runtime.h>
#include <hip/hip_bf16.h>

#define BSZ   4096
#define NCON  8192
#define DFEAT 256
#define INV_T 14.285714285714285f   // 1/0.07; also the analytic row max (self-dot==1)

typedef __attribute__((ext_vector_type(8))) short short8;
typedef __attribute__((ext_vector_type(4))) float f32x4;

// ws layout:
//   [0, 4MB)           : contrast bf16 [NCON][DFEAT]  (rows 0..4095 = anchor view0)
//   [4MB, 4MB+48KB)    : f32 accumulators: S[4096], A[4096], B[4096]

__global__ __launch_bounds__(256) void k_prep(const float* __restrict__ feat,
                                              __hip_bfloat16* __restrict__ con,
                                              float* __restrict__ acc) {
    int idx = blockIdx.x * 256 + threadIdx.x;
    if (idx < NCON * DFEAT) {
        int j = idx >> 8;          // contrast row
        int k = idx & 255;
        // contrast row j: j<BSZ -> features[j, view0]; else features[j-BSZ, view1]
        int src = (j < BSZ) ? ((j * 2) * DFEAT + k)
                            : (((j - BSZ) * 2 + 1) * DFEAT + k);
        con[idx] = __float2bfloat16(feat[src]);
    }
    if (idx < 3 * BSZ) acc[idx] = 0.0f;
}

__global__ __launch_bounds__(256) void k_main(const __hip_bfloat16* __restrict__ con,
                                              const float* __restrict__ va,
                                              const int* __restrict__ dia,
                                              const int* __restrict__ thr_ptr,
                                              float* __restrict__ Srow,
                                              float* __restrict__ Arow,
                                              float* __restrict__ Brow) {
    const int tid  = threadIdx.x;
    const int lane = tid & 63;
    const int wave = tid >> 6;
    const int m0   = blockIdx.y * 64 + wave * 16;   // anchor rows (this wave: 16)
    const int n0   = blockIdx.x * 64;               // contrast cols (this wave: 64)

    // thres: hedge int vs float encoding of the Python scalar
    int raw = *thr_ptr;
    float t = (raw > 0 && raw < 100000) ? (float)raw : __int_as_float(raw);
    float thres2 = t * t;

    const short* cs = (const short*)con;

    f32x4 acc[4];
    #pragma unroll
    for (int s = 0; s < 4; ++s) acc[s] = (f32x4){0.f, 0.f, 0.f, 0.f};

    // A frag: lane holds A[m = lane&15][k = (lane>>4)*8 + i], i=0..7
    // B frag: lane holds B[k = (lane>>4)*8 + i][n = lane&15] = con[n0+n][k...]
    const int koff = (lane >> 4) * 8;
    const short* aptr = cs + (size_t)(m0 + (lane & 15)) * DFEAT + koff;
    const short* bptr = cs + (size_t)(n0 + (lane & 15)) * DFEAT + koff;

    #pragma unroll
    for (int kk = 0; kk < 8; ++kk) {
        short8 af = *(const short8*)(aptr + kk * 32);
        #pragma unroll
        for (int s = 0; s < 4; ++s) {
            short8 bf = *(const short8*)(bptr + (size_t)s * 16 * DFEAT + kk * 32);
            acc[s] = __builtin_amdgcn_mfma_f32_16x16x32_bf16(af, bf, acc[s], 0, 0, 0);
        }
    }

    // Epilogue. D layout: col = lane&15 (+16*s), row = (lane>>4)*4 + r.
    const int rowbase = m0 + ((lane >> 4) << 2);
    const int colbase = n0 + (lane & 15);

    float vix[4], viy[4]; int di[4];
    #pragma unroll
    for (int r = 0; r < 4; ++r) {
        int i = rowbase + r;
        vix[r] = va[2 * i];
        viy[r] = va[2 * i + 1];
        di[r]  = dia[i];
    }

    float sp[4] = {0.f, 0.f, 0.f, 0.f};
    float ap[4] = {0.f, 0.f, 0.f, 0.f};
    float bp[4] = {0.f, 0.f, 0.f, 0.f};

    #pragma unroll
    for (int s = 0; s < 4; ++s) {
        int j  = colbase + s * 16;       // global col in [0, 8192)
        int jm = j & (BSZ - 1);          // mask index
        float vjx = va[2 * jm], vjy = va[2 * jm + 1];
        int dj = dia[jm];
        #pragma unroll
        for (int r = 0; r < 4; ++r) {
            int i = rowbase + r;
            float l = (acc[s][r] - 1.0f) * INV_T;      // logits - C, C = 1/T
            bool lm = (j != i);                         // logits_mask
            float e = lm ? __expf(l) : 0.0f;
            float dx = vix[r] - vjx, dy = viy[r] - vjy;
            bool m  = (i == jm) | (di[r] == dj) | (dx * dx + dy * dy < thres2);
            sp[r] += e;
            if (m & lm) { ap[r] += l; bp[r] += 1.0f; }
        }
    }

    // row-reduce across the 16 lanes of each row group (lanes differ in bits 0..3)
    #pragma unroll
    for (int r = 0; r < 4; ++r) {
        float s = sp[r], a = ap[r], b = bp[r];
        #pragma unroll
        for (int off = 1; off < 16; off <<= 1) {
            s += __shfl_xor(s, off, 64);
            a += __shfl_xor(a, off, 64);
            b += __shfl_xor(b, off, 64);
        }
        if ((lane & 15) == 0) {
            int i = rowbase + r;
            atomicAdd(&Srow[i], s);
            atomicAdd(&Arow[i], a);
            atomicAdd(&Brow[i], b);
        }
    }
}

__global__ __launch_bounds__(256) void k_final(const float* __restrict__ S,
                                               const float* __restrict__ A,
                                               const float* __restrict__ B,
                                               float* __restrict__ out) {
    __shared__ float red[256];
    float sum = 0.f;
    for (int i = threadIdx.x; i < BSZ; i += 256) {
        float b = B[i];
        float v = (A[i] - b * logf(S[i] + 1e-10f)) / (b + 1e-10f);
        sum += -v;
    }
    red[threadIdx.x] = sum;
    __syncthreads();
    for (int s = 128; s > 0; s >>= 1) {
        if (threadIdx.x < s) red[threadIdx.x] += red[threadIdx.x + s];
        __syncthreads();
    }
    if (threadIdx.x == 0) out[0] = red[0] / (float)BSZ;
}

extern "C" void kernel_launch(void* const* d_in, const int* in_sizes, int n_in,
                              void* d_out, int out_size, void* d_ws, size_t ws_size,
                              hipStream_t stream) {
    const float* feat = (const float*)d_in[0];
    const float* va   = (const float*)d_in[1];
    const int*   dia  = (const int*)d_in[2];
    const int*   thr  = (const int*)d_in[3];

    __hip_bfloat16* con = (__hip_bfloat16*)d_ws;
    float* acc = (float*)((char*)d_ws + (size_t)NCON * DFEAT * 2);
    float* out = (float*)d_out;

    k_prep<<<(NCON * DFEAT + 255) / 256, 256, 0, stream>>>(feat, con, acc);

    dim3 grid(NCON / 64, BSZ / 64);
    k_main<<<grid, 256, 0, stream>>>(con, va, dia, thr,
                                     acc, acc + BSZ, acc + 2 * BSZ);

    k_final<<<1, 256, 0, stream>>>(acc, acc + BSZ, acc + 2 * BSZ, out);
}

// Round 3
// 117.633 us; speedup vs baseline: 1.7357x; 1.7357x over previous
//
#include <hip/hip_runtime.h>
#include <hip/hip_bf16.h>

#define BSZ   4096
#define NCON  8192
#define DFEAT 256
#define INV_T 14.285714285714285f   // 1/T; also the analytic row max (self-dot == 1)

#define BM 128
#define BN 128
#define BK 64

typedef __attribute__((ext_vector_type(8))) short short8;
typedef __attribute__((ext_vector_type(4))) float f32x4;

__device__ __forceinline__ unsigned short f2bf(float f) {
    __hip_bfloat16 h = __float2bfloat16(f);
    return *reinterpret_cast<unsigned short*>(&h);
}

__device__ __forceinline__ void gload_lds16(const void* g, void* l) {
    __builtin_amdgcn_global_load_lds(
        (const __attribute__((address_space(1))) unsigned int*)g,
        (__attribute__((address_space(3))) unsigned int*)l,
        16, 0, 0);
}

// ws layout: [0, 4MB) contrast bf16 [NCON][DFEAT]; then f32 S[4096], A[4096], B[4096]

__global__ __launch_bounds__(256) void k_prep(const float* __restrict__ feat,
                                              unsigned short* __restrict__ con,
                                              float* __restrict__ acc) {
    int idx = blockIdx.x * 256 + threadIdx.x;      // 524288 elems / 4 per thread
    int e = idx * 4;
    int j = e >> 8;                                // contrast row
    int k = e & 255;
    int src = (j < BSZ) ? ((j * 2) * DFEAT + k)
                        : (((j - BSZ) * 2 + 1) * DFEAT + k);
    float4 f = *(const float4*)(feat + src);
    ushort4 o;
    o.x = f2bf(f.x);
    o.y = f2bf(f.y);
    o.z = f2bf(f.z);
    o.w = f2bf(f.w);
    *(ushort4*)(con + e) = o;
    if (idx < 3 * BSZ) acc[idx] = 0.0f;
}

__global__ __launch_bounds__(256) void k_main(const __hip_bfloat16* __restrict__ conp,
                                              const float* __restrict__ va,
                                              const int* __restrict__ dia,
                                              const int* __restrict__ thr_ptr,
                                              float* __restrict__ Srow,
                                              float* __restrict__ Arow,
                                              float* __restrict__ Brow) {
    __shared__ short lA[BM * BK];
    __shared__ short lB[BN * BK];
    __shared__ float s_vrx[BM], s_vry[BM], s_vcx[BN], s_vcy[BN];
    __shared__ int   s_dr[BM], s_dc[BN];

    const int tid  = threadIdx.x;
    const int lane = tid & 63;
    const int wv   = tid >> 6;
    const int wr   = wv >> 1;            // wave row (0..1)
    const int wc   = wv & 1;             // wave col (0..1)
    const int l15  = lane & 15;
    const int lhi  = lane >> 4;
    const int brow = blockIdx.y * BM;
    const int bcol = blockIdx.x * BN;
    const int jbase = bcol & (BSZ - 1);
    const short* cs = (const short*)conp;

    // stage epilogue metadata (no barrier needed yet; K-loop barriers cover it)
    if (tid < BM) {
        int i = brow + tid;
        s_vrx[tid] = va[2 * i];
        s_vry[tid] = va[2 * i + 1];
        s_dr[tid]  = dia[i];
    } else {
        int c = tid - BM;
        int jm = jbase + c;
        s_vcx[c] = va[2 * jm];
        s_vcy[c] = va[2 * jm + 1];
        s_dc[c]  = dia[jm];
    }

    int raw = *thr_ptr;
    float t = (raw > 0 && raw < 100000) ? (float)raw : __int_as_float(raw);
    float thres2 = t * t;

    f32x4 acc[4][4];
    #pragma unroll
    for (int m = 0; m < 4; ++m)
        #pragma unroll
        for (int n = 0; n < 4; ++n)
            acc[m][n] = (f32x4){0.f, 0.f, 0.f, 0.f};

    // ---- K loop: 4 steps of BK=64 ----
    for (int t4 = 0; t4 < DFEAT / BK; ++t4) {
        // stage A/B tiles: linear LDS dest, inverse-swizzled global source
        #pragma unroll
        for (int i = 0; i < 4; ++i) {
            int e   = i * 2048 + tid * 8;          // element in [0, 8192)
            int row = e >> 6;                      // 0..127
            int col = e & 63;
            int scol = col ^ ((row & 7) << 3);     // involution pre-swizzle
            gload_lds16(cs + (size_t)(brow + row) * DFEAT + t4 * BK + scol, lA + e);
            gload_lds16(cs + (size_t)(bcol + row) * DFEAT + t4 * BK + scol, lB + e);
        }
        __syncthreads();   // staging drained (compiler emits vmcnt(0) before barrier)

        #pragma unroll
        for (int ks = 0; ks < 2; ++ks) {
            const int colb = (ks * 32 + lhi * 8) * 2;   // byte col of fragment
            short8 af[4], bfr[4];
            #pragma unroll
            for (int m = 0; m < 4; ++m) {
                int row = wr * 64 + m * 16 + l15;
                af[m] = *(const short8*)((const char*)lA + row * 128 + (colb ^ ((row & 7) << 4)));
            }
            #pragma unroll
            for (int n = 0; n < 4; ++n) {
                int row = wc * 64 + n * 16 + l15;
                bfr[n] = *(const short8*)((const char*)lB + row * 128 + (colb ^ ((row & 7) << 4)));
            }
            #pragma unroll
            for (int m = 0; m < 4; ++m)
                #pragma unroll
                for (int n = 0; n < 4; ++n)
                    acc[m][n] = __builtin_amdgcn_mfma_f32_16x16x32_bf16(af[m], bfr[n], acc[m][n], 0, 0, 0);
        }
        __syncthreads();   // compute done before next staging overwrites
    }

    // ---- epilogue ----
    #pragma unroll
    for (int m = 0; m < 4; ++m) {
        const int il0 = wr * 64 + m * 16 + lhi * 4;   // local row base
        float sp[4] = {0.f, 0.f, 0.f, 0.f};
        float ap[4] = {0.f, 0.f, 0.f, 0.f};
        float bp[4] = {0.f, 0.f, 0.f, 0.f};
        #pragma unroll
        for (int n = 0; n < 4; ++n) {
            const int jl = wc * 64 + n * 16 + l15;    // local col
            const int j  = bcol + jl;                 // global col in [0, 8192)
            float vjx = s_vcx[jl], vjy = s_vcy[jl];
            int dj = s_dc[jl];
            #pragma unroll
            for (int r = 0; r < 4; ++r) {
                const int il = il0 + r;
                const int i  = brow + il;             // global anchor row
                float l = (acc[m][n][r] - 1.0f) * INV_T;
                bool lm = (j != i);
                float e = lm ? __expf(l) : 0.0f;
                float dx = s_vrx[il] - vjx, dy = s_vry[il] - vjy;
                bool mk = (i == jbase + jl) | (s_dr[il] == dj) | (dx * dx + dy * dy < thres2);
                sp[r] += e;
                if (mk & lm) { ap[r] += l; bp[r] += 1.0f; }
            }
        }
        #pragma unroll
        for (int r = 0; r < 4; ++r) {
            float s = sp[r], a = ap[r], b = bp[r];
            #pragma unroll
            for (int off = 1; off < 16; off <<= 1) {
                s += __shfl_xor(s, off, 64);
                a += __shfl_xor(a, off, 64);
                b += __shfl_xor(b, off, 64);
            }
            if (l15 == 0) {
                int i = brow + il0 + r;
                atomicAdd(&Srow[i], s);
                atomicAdd(&Arow[i], a);
                atomicAdd(&Brow[i], b);
            }
        }
    }
}

__global__ __launch_bounds__(256) void k_final(const float* __restrict__ S,
                                               const float* __restrict__ A,
                                               const float* __restrict__ B,
                                               float* __restrict__ out) {
    __shared__ float red[256];
    float sum = 0.f;
    for (int i = threadIdx.x; i < BSZ; i += 256) {
        float b = B[i];
        float v = (A[i] - b * logf(S[i] + 1e-10f)) / (b + 1e-10f);
        sum += -v;
    }
    red[threadIdx.x] = sum;
    __syncthreads();
    for (int s = 128; s > 0; s >>= 1) {
        if (threadIdx.x < s) red[threadIdx.x] += red[threadIdx.x + s];
        __syncthreads();
    }
    if (threadIdx.x == 0) out[0] = red[0] / (float)BSZ;
}

extern "C" void kernel_launch(void* const* d_in, const int* in_sizes, int n_in,
                              void* d_out, int out_size, void* d_ws, size_t ws_size,
                              hipStream_t stream) {
    const float* feat = (const float*)d_in[0];
    const float* va   = (const float*)d_in[1];
    const int*   dia  = (const int*)d_in[2];
    const int*   thr  = (const int*)d_in[3];

    unsigned short* con = (unsigned short*)d_ws;
    float* acc = (float*)((char*)d_ws + (size_t)NCON * DFEAT * 2);
    float* out = (float*)d_out;

    k_prep<<<(NCON * DFEAT / 4 + 255) / 256, 256, 0, stream>>>(feat, con, acc);

    dim3 grid(NCON / BN, BSZ / BM);
    k_main<<<grid, 256, 0, stream>>>((const __hip_bfloat16*)con, va, dia, thr,
                                     acc, acc + BSZ, acc + 2 * BSZ);

    k_final<<<1, 256, 0, stream>>>(acc, acc + BSZ, acc + 2 * BSZ, out);
}

// Round 4
// 68.205 us; speedup vs baseline: 2.9936x; 1.7247x over previous
//
#include <hip/hip_runtime.h>
#include <hip/hip_bf16.h>

#define BSZ   4096
#define NCON  8192
#define DFEAT 256
#define INV_T 14.285714285714285f   // 1/T; also the analytic row max (self-dot == 1)

#define BT 128   // block tile in both i (anchor) and j (contrast)
#define BK 64

typedef __attribute__((ext_vector_type(8))) short short8;
typedef __attribute__((ext_vector_type(4))) float f32x4;

__device__ __forceinline__ unsigned short f2bf(float f) {
    __hip_bfloat16 h = __float2bfloat16(f);
    return *reinterpret_cast<unsigned short*>(&h);
}

__device__ __forceinline__ void gload_lds16(const void* g, void* l) {
    __builtin_amdgcn_global_load_lds(
        (const __attribute__((address_space(1))) unsigned int*)g,
        (__attribute__((address_space(3))) unsigned int*)l,
        16, 0, 0);
}

// ws layout: [0, 4MB) contrast bf16 [NCON][DFEAT]; then f32 S[4096], A[4096], B[4096]

__global__ __launch_bounds__(256) void k_prep(const float* __restrict__ feat,
                                              unsigned short* __restrict__ con,
                                              float* __restrict__ acc) {
    int idx = blockIdx.x * 256 + threadIdx.x;
    int e = idx * 4;
    int j = e >> 8;
    int k = e & 255;
    int src = (j < BSZ) ? ((j * 2) * DFEAT + k)
                        : (((j - BSZ) * 2 + 1) * DFEAT + k);
    float4 f = *(const float4*)(feat + src);
    ushort4 o;
    o.x = f2bf(f.x); o.y = f2bf(f.y); o.z = f2bf(f.z); o.w = f2bf(f.w);
    *(ushort4*)(con + e) = o;
    if (idx < 3 * BSZ) acc[idx] = 0.0f;
}

__global__ __launch_bounds__(256, 2) void k_main(const __hip_bfloat16* __restrict__ conp,
                                                 const float* __restrict__ va,
                                                 const int* __restrict__ dia,
                                                 const int* __restrict__ thr_ptr,
                                                 float* __restrict__ Srow,
                                                 float* __restrict__ Arow,
                                                 float* __restrict__ Brow) {
    __shared__ short lX[2][BT * BK];   // contrast (j) tiles, double-buffered
    __shared__ short lY[2][BT * BK];   // anchor (i) tiles, double-buffered
    __shared__ float s_vjx[BT], s_vjy[BT], s_vix[BT], s_viy[BT];
    __shared__ int   s_dj[BT], s_di[BT];

    const int tid  = threadIdx.x;
    const int lane = tid & 63;
    const int wv   = tid >> 6;
    const int wj   = wv >> 1;           // wave j-split (0..1)
    const int wi   = wv & 1;            // wave i-split (0..1)
    const int l15  = lane & 15;
    const int hi   = lane >> 4;
    const int jbase = blockIdx.x * BT;  // contrast cols [0, 8192)
    const int ibase = blockIdx.y * BT;  // anchor rows  [0, 4096)
    const short* cs = (const short*)conp;

    // epilogue metadata (any K-loop barrier covers completion)
    if (tid < BT) {
        int jl = tid, jm = (jbase + jl) & (BSZ - 1);
        s_vjx[jl] = va[2 * jm]; s_vjy[jl] = va[2 * jm + 1]; s_dj[jl] = dia[jm];
    } else {
        int il = tid - BT, i = ibase + il;
        s_vix[il] = va[2 * i]; s_viy[il] = va[2 * i + 1]; s_di[il] = dia[i];
    }

    int raw = *thr_ptr;
    float t_ = (raw > 0 && raw < 100000) ? (float)raw : __int_as_float(raw);
    float thres2 = t_ * t_;

    f32x4 acc[4][4];   // [m = j-tile][n = i-tile]
    #pragma unroll
    for (int m = 0; m < 4; ++m)
        #pragma unroll
        for (int n = 0; n < 4; ++n)
            acc[m][n] = (f32x4){0.f, 0.f, 0.f, 0.f};

    auto stage = [&](int buf, int t) {
        #pragma unroll
        for (int q = 0; q < 4; ++q) {
            int e   = q * 2048 + tid * 8;
            int row = e >> 6;
            int col = e & 63;
            int scol = col ^ ((row & 7) << 3);   // involution pre-swizzle (elements)
            gload_lds16(cs + (size_t)(jbase + row) * DFEAT + t * BK + scol, &lX[buf][e]);
            gload_lds16(cs + (size_t)(ibase + row) * DFEAT + t * BK + scol, &lY[buf][e]);
        }
    };

    stage(0, 0);
    __syncthreads();

    for (int t = 0; t < DFEAT / BK; ++t) {
        if (t < DFEAT / BK - 1) stage((t + 1) & 1, t + 1);   // issue next tile FIRST
        const short* bufX = &lX[t & 1][0];
        const short* bufY = &lY[t & 1][0];
        #pragma unroll
        for (int ks = 0; ks < 2; ++ks) {
            const int colb = (ks * 32 + hi * 8) * 2;
            short8 xf[4], yf[4];
            #pragma unroll
            for (int m = 0; m < 4; ++m) {
                int row = wj * 64 + m * 16 + l15;
                xf[m] = *(const short8*)((const char*)bufX + row * 128 + (colb ^ ((row & 7) << 4)));
            }
            #pragma unroll
            for (int n = 0; n < 4; ++n) {
                int row = wi * 64 + n * 16 + l15;
                yf[n] = *(const short8*)((const char*)bufY + row * 128 + (colb ^ ((row & 7) << 4)));
            }
            #pragma unroll
            for (int m = 0; m < 4; ++m)
                #pragma unroll
                for (int n = 0; n < 4; ++n)
                    acc[m][n] = __builtin_amdgcn_mfma_f32_16x16x32_bf16(xf[m], yf[n], acc[m][n], 0, 0, 0);
        }
        __syncthreads();   // drains this iter's stage loads; next iter reads them
    }

    // ---- epilogue: D[j][i]; lane holds 4 j's (hi*4+r) per m, i = n*16 + l15 ----
    float vix[4], viy[4]; int di[4];
    #pragma unroll
    for (int n = 0; n < 4; ++n) {
        int il = wi * 64 + n * 16 + l15;
        vix[n] = s_vix[il]; viy[n] = s_viy[il]; di[n] = s_di[il];
    }

    float sp[4] = {0.f, 0.f, 0.f, 0.f};
    float ap[4] = {0.f, 0.f, 0.f, 0.f};
    float bp[4] = {0.f, 0.f, 0.f, 0.f};

    #pragma unroll
    for (int m = 0; m < 4; ++m) {
        #pragma unroll
        for (int r = 0; r < 4; ++r) {
            const int jl = wj * 64 + m * 16 + hi * 4 + r;
            const int j  = jbase + jl;
            const int jm = j & (BSZ - 1);
            float vjx = s_vjx[jl], vjy = s_vjy[jl];
            int dj = s_dj[jl];
            #pragma unroll
            for (int n = 0; n < 4; ++n) {
                const int i = ibase + wi * 64 + n * 16 + l15;
                float l = (acc[m][n][r] - 1.0f) * INV_T;
                bool lm = (j != i);
                float e = lm ? __expf(l) : 0.0f;
                float dx = vix[n] - vjx, dy = viy[n] - vjy;
                bool mk = (i == jm) | (di[n] == dj) | (dx * dx + dy * dy < thres2);
                sp[n] += e;
                if (mk & lm) { ap[n] += l; bp[n] += 1.0f; }
            }
        }
    }

    #pragma unroll
    for (int n = 0; n < 4; ++n) {
        float s = sp[n], a = ap[n], b = bp[n];
        s += __shfl_xor(s, 16, 64);  a += __shfl_xor(a, 16, 64);  b += __shfl_xor(b, 16, 64);
        s += __shfl_xor(s, 32, 64);  a += __shfl_xor(a, 32, 64);  b += __shfl_xor(b, 32, 64);
        if (hi == 0) {
            int i = ibase + wi * 64 + n * 16 + l15;
            atomicAdd(&Srow[i], s);
            atomicAdd(&Arow[i], a);
            atomicAdd(&Brow[i], b);
        }
    }
}

__global__ __launch_bounds__(256) void k_final(const float* __restrict__ S,
                                               const float* __restrict__ A,
                                               const float* __restrict__ B,
                                               float* __restrict__ out) {
    __shared__ float red[256];
    float sum = 0.f;
    for (int i = threadIdx.x; i < BSZ; i += 256) {
        float b = B[i];
        float v = (A[i] - b * logf(S[i] + 1e-10f)) / (b + 1e-10f);
        sum += -v;
    }
    red[threadIdx.x] = sum;
    __syncthreads();
    for (int s = 128; s > 0; s >>= 1) {
        if (threadIdx.x < s) red[threadIdx.x] += red[threadIdx.x + s];
        __syncthreads();
    }
    if (threadIdx.x == 0) out[0] = red[0] / (float)BSZ;
}

extern "C" void kernel_launch(void* const* d_in, const int* in_sizes, int n_in,
                              void* d_out, int out_size, void* d_ws, size_t ws_size,
                              hipStream_t stream) {
    const float* feat = (const float*)d_in[0];
    const float* va   = (const float*)d_in[1];
    const int*   dia  = (const int*)d_in[2];
    const int*   thr  = (const int*)d_in[3];

    unsigned short* con = (unsigned short*)d_ws;
    float* acc = (float*)((char*)d_ws + (size_t)NCON * DFEAT * 2);
    float* out = (float*)d_out;

    k_prep<<<(NCON * DFEAT / 4 + 255) / 256, 256, 0, stream>>>(feat, con, acc);

    dim3 grid(NCON / BT, BSZ / BT);
    k_main<<<grid, 256, 0, stream>>>((const __hip_bfloat16*)con, va, dia, thr,
                                     acc, acc + BSZ, acc + 2 * BSZ);

    k_final<<<1, 256, 0, stream>>>(acc, acc + BSZ, acc + 2 * BSZ, out);
}

// Round 5
// 55.048 us; speedup vs baseline: 3.7091x; 1.2390x over previous
//
#include <hip/hip_runtime.h>
#include <hip/hip_bf16.h>

#define BSZ   4096
#define NCON  8192
#define DFEAT 256
#define INV_T 14.285714285714285f   // 1/T; also the analytic row max (self-dot == 1)

#define BJ 128   // block tile in j (contrast)
#define BI 128   // block tile in i (anchor); each of 4 waves owns 32 i-rows
#define BK 64

typedef __attribute__((ext_vector_type(8))) short short8;
typedef __attribute__((ext_vector_type(4))) float f32x4;

__device__ __forceinline__ unsigned short f2bf(float f) {
    __hip_bfloat16 h = __float2bfloat16(f);
    return *reinterpret_cast<unsigned short*>(&h);
}

__device__ __forceinline__ void gload_lds16(const void* g, void* l) {
    __builtin_amdgcn_global_load_lds(
        (const __attribute__((address_space(1))) unsigned int*)g,
        (__attribute__((address_space(3))) unsigned int*)l,
        16, 0, 0);
}

// ws layout: [0, 4MB) contrast bf16 [NCON][DFEAT]; then f32 S[4096], A[4096], B[4096]

__global__ __launch_bounds__(256) void k_prep(const float* __restrict__ feat,
                                              unsigned short* __restrict__ con,
                                              float* __restrict__ acc) {
    int idx = blockIdx.x * 256 + threadIdx.x;
    int e = idx * 4;
    int j = e >> 8;
    int k = e & 255;
    int src = (j < BSZ) ? ((j * 2) * DFEAT + k)
                        : (((j - BSZ) * 2 + 1) * DFEAT + k);
    float4 f = *(const float4*)(feat + src);
    ushort4 o;
    o.x = f2bf(f.x); o.y = f2bf(f.y); o.z = f2bf(f.z); o.w = f2bf(f.w);
    *(ushort4*)(con + e) = o;
    if (idx < 3 * BSZ) acc[idx] = 0.0f;
}

__global__ __launch_bounds__(256, 3) void k_main(const __hip_bfloat16* __restrict__ conp,
                                                 const float* __restrict__ va,
                                                 const int* __restrict__ dia,
                                                 const int* __restrict__ thr_ptr,
                                                 float* __restrict__ Srow,
                                                 float* __restrict__ Arow,
                                                 float* __restrict__ Brow) {
    __shared__ short lX[2][BJ * BK];   // contrast (j) tiles only, double-buffered: 32 KB
    __shared__ float s_vjx[BJ], s_vjy[BJ];
    __shared__ int   s_dj[BJ];

    const int tid  = threadIdx.x;
    const int lane = tid & 63;
    const int wv   = tid >> 6;
    const int l15  = lane & 15;
    const int hi   = lane >> 4;
    const int jbase = blockIdx.x * BJ;              // [0, 8192)
    const int ibase = blockIdx.y * BI + wv * 32;    // this wave's 32 anchor rows
    const short* cs = (const short*)conp;

    // j-side epilogue metadata (completion covered by first K-loop barrier)
    if (tid < BJ) {
        int jm = (jbase + tid) & (BSZ - 1);
        s_vjx[tid] = va[2 * jm]; s_vjy[tid] = va[2 * jm + 1]; s_dj[tid] = dia[jm];
    }

    int raw = *thr_ptr;
    float t_ = (raw > 0 && raw < 100000) ? (float)raw : __int_as_float(raw);
    float thres2 = t_ * t_;

    f32x4 acc[8][2];   // [m = j-frag][n = i-frag]
    #pragma unroll
    for (int m = 0; m < 8; ++m)
        #pragma unroll
        for (int n = 0; n < 2; ++n)
            acc[m][n] = (f32x4){0.f, 0.f, 0.f, 0.f};

    auto stageX = [&](int buf, int t) {
        #pragma unroll
        for (int q = 0; q < 4; ++q) {
            int e   = q * 2048 + tid * 8;
            int row = e >> 6;
            int col = e & 63;
            int scol = col ^ ((row & 7) << 3);   // involution pre-swizzle (elements)
            gload_lds16(cs + (size_t)(jbase + row) * DFEAT + t * BK + scol, &lX[buf][e]);
        }
    };

    // Y (anchor) fragments direct from global: rows ibase + n*16 + l15, 16B chunks
    const short* yrow0 = cs + (size_t)(ibase + l15) * DFEAT + hi * 8;
    auto loadY = [&](int t, short8 y[2][2]) {
        #pragma unroll
        for (int n = 0; n < 2; ++n)
            #pragma unroll
            for (int ks = 0; ks < 2; ++ks)
                y[n][ks] = *(const short8*)(yrow0 + (size_t)n * 16 * DFEAT + t * BK + ks * 32);
    };

    short8 ycur[2][2], ynxt[2][2];
    stageX(0, 0);
    loadY(0, ycur);
    __syncthreads();

    for (int t = 0; t < DFEAT / BK; ++t) {
        if (t < DFEAT / BK - 1) {
            stageX((t + 1) & 1, t + 1);     // issue next X tile FIRST
            loadY(t + 1, ynxt);             // prefetch next Y frags
        }
        const char* bufX = (const char*)&lX[t & 1][0];
        #pragma unroll
        for (int ks = 0; ks < 2; ++ks) {
            const int colb = (ks * 32 + hi * 8) * 2;
            short8 xf[8];
            #pragma unroll
            for (int m = 0; m < 8; ++m) {
                int row = m * 16 + l15;
                xf[m] = *(const short8*)(bufX + row * 128 + (colb ^ ((row & 7) << 4)));
            }
            #pragma unroll
            for (int m = 0; m < 8; ++m)
                #pragma unroll
                for (int n = 0; n < 2; ++n)
                    acc[m][n] = __builtin_amdgcn_mfma_f32_16x16x32_bf16(xf[m], ycur[n][ks], acc[m][n], 0, 0, 0);
        }
        __syncthreads();   // drains this iter's stage; next iter reads it
        #pragma unroll
        for (int n = 0; n < 2; ++n)
            #pragma unroll
            for (int ks = 0; ks < 2; ++ks)
                ycur[n][ks] = ynxt[n][ks];
    }

    // ---- epilogue: D[j][i]; lane holds j = m*16 + hi*4 + r, i = n*16 + l15 ----
    float vix[2], viy[2]; int di[2];
    #pragma unroll
    for (int n = 0; n < 2; ++n) {
        int i = ibase + n * 16 + l15;
        vix[n] = va[2 * i]; viy[n] = va[2 * i + 1]; di[n] = dia[i];
    }

    float sp[2] = {0.f, 0.f};
    float ap[2] = {0.f, 0.f};
    float bp[2] = {0.f, 0.f};

    #pragma unroll
    for (int m = 0; m < 8; ++m) {
        #pragma unroll
        for (int r = 0; r < 4; ++r) {
            const int jl = m * 16 + hi * 4 + r;
            const int j  = jbase + jl;
            const int jm = j & (BSZ - 1);
            float vjx = s_vjx[jl], vjy = s_vjy[jl];
            int dj = s_dj[jl];
            #pragma unroll
            for (int n = 0; n < 2; ++n) {
                const int i = ibase + n * 16 + l15;
                float l = (acc[m][n][r] - 1.0f) * INV_T;
                bool lm = (j != i);
                float e = lm ? __expf(l) : 0.0f;
                float dx = vix[n] - vjx, dy = viy[n] - vjy;
                bool mk = (i == jm) | (di[n] == dj) | (dx * dx + dy * dy < thres2);
                sp[n] += e;
                if (mk & lm) { ap[n] += l; bp[n] += 1.0f; }
            }
        }
    }

    #pragma unroll
    for (int n = 0; n < 2; ++n) {
        float s = sp[n], a = ap[n], b = bp[n];
        s += __shfl_xor(s, 16, 64);  a += __shfl_xor(a, 16, 64);  b += __shfl_xor(b, 16, 64);
        s += __shfl_xor(s, 32, 64);  a += __shfl_xor(a, 32, 64);  b += __shfl_xor(b, 32, 64);
        if (hi == 0) {
            int i = ibase + n * 16 + l15;
            atomicAdd(&Srow[i], s);
            atomicAdd(&Arow[i], a);
            atomicAdd(&Brow[i], b);
        }
    }
}

__global__ __launch_bounds__(256) void k_final(const float* __restrict__ S,
                                               const float* __restrict__ A,
                                               const float* __restrict__ B,
                                               float* __restrict__ out) {
    __shared__ float red[256];
    float sum = 0.f;
    for (int i = threadIdx.x; i < BSZ; i += 256) {
        float b = B[i];
        float v = (A[i] - b * logf(S[i] + 1e-10f)) / (b + 1e-10f);
        sum += -v;
    }
    red[threadIdx.x] = sum;
    __syncthreads();
    for (int s = 128; s > 0; s >>= 1) {
        if (threadIdx.x < s) red[threadIdx.x] += red[threadIdx.x + s];
        __syncthreads();
    }
    if (threadIdx.x == 0) out[0] = red[0] / (float)BSZ;
}

extern "C" void kernel_launch(void* const* d_in, const int* in_sizes, int n_in,
                              void* d_out, int out_size, void* d_ws, size_t ws_size,
                              hipStream_t stream) {
    const float* feat = (const float*)d_in[0];
    const float* va   = (const float*)d_in[1];
    const int*   dia  = (const int*)d_in[2];
    const int*   thr  = (const int*)d_in[3];

    unsigned short* con = (unsigned short*)d_ws;
    float* acc = (float*)((char*)d_ws + (size_t)NCON * DFEAT * 2);
    float* out = (float*)d_out;

    k_prep<<<(NCON * DFEAT / 4 + 255) / 256, 256, 0, stream>>>(feat, con, acc);

    dim3 grid(NCON / BJ, BSZ / BI);
    k_main<<<grid, 256, 0, stream>>>((const __hip_bfloat16*)con, va, dia, thr,
                                     acc, acc + BSZ, acc + 2 * BSZ);

    k_final<<<1, 256, 0, stream>>>(acc, acc + BSZ, acc + 2 * BSZ, out);
}